// Round 3
// baseline (9099.648 us; speedup 1.0000x reference)
//
#include <hip/hip_runtime.h>
#include <math.h>

#define BDIM 512
#define BR   32
#define D    128
#define SPD  132      // padded LDS row stride (doubles)
#define TT   32
#define NB   8
#define NL   3

__device__ __forceinline__ double c19_act_d(double x) {
    const double PI_D = 3.14159265358979323846;
    const double L6   = 6.0 * PI_D;
    double scaled = x * (1.0 / PI_D);
    double n = floor(scaled);
    double t = scaled - n;
    double h = t * (1.0 - t);
    double halfn = n * 0.5;
    double fr = halfn - floor(halfn);   // 0.0 (even n) or 0.5 (odd n)
    double sgn = (fr < 0.25) ? 1.0 : -1.0;
    double core = PI_D * (sgn * h + 4.0 * h * h);
    double r = core;
    r = (x <= -L6) ? (x + L6) : r;
    r = (x >=  L6) ? (x - L6) : r;
    return r;
}

__global__ __launch_bounds__(BDIM, 1) void miniphi_kernel(
    const float* __restrict__ x,  const float* __restrict__ Wi, const float* __restrict__ bi,
    const float* __restrict__ Wo, const float* __restrict__ bo,
    const float* __restrict__ g_state, const float* __restrict__ b_state,
    const float* __restrict__ Ws, const float* __restrict__ bs,
    const float* __restrict__ gs, const float* __restrict__ betas,
    float* __restrict__ out)
{
    __shared__ double sStateD[BR][SPD];   // recurrent state, fp64, never rounded
    __shared__ double sAD[BR][SPD];       // LN output, fp64
    __shared__ float sW[D][D];
    __shared__ float sWi[NB][D];
    __shared__ float sWo[D][NB];
    __shared__ float sBi[D], sGst[D], sBst[D];
    __shared__ float sBs[NL][D], sGs[NL][D], sBe[NL][D];
    __shared__ float sBo[NB];

    const int tid = threadIdx.x;

    for (int i = tid; i < NB * D; i += BDIM) sWi[i / D][i % D] = Wi[i];
    for (int i = tid; i < D * NB; i += BDIM) sWo[i / NB][i % NB] = Wo[i];
    for (int i = tid; i < D; i += BDIM) { sBi[i] = bi[i]; sGst[i] = g_state[i]; sBst[i] = b_state[i]; }
    for (int i = tid; i < NL * D; i += BDIM) { sBs[i / D][i % D] = bs[i]; sGs[i / D][i % D] = gs[i]; sBe[i / D][i % D] = betas[i]; }
    if (tid < NB) sBo[tid] = bo[tid];
    for (int i = tid; i < BR * D; i += BDIM) sStateD[i / D][i % D] = 0.0;
    __syncthreads();

    const int rLN = tid >> 4;        // 0..31 : row for LN phases (16 lanes/row)
    const int sLN = tid & 15;        // 0..15 : 8-element slice within row
    const int d0  = sLN * 8;
    const int rg  = tid >> 5;        // 0..15 : GEMM row group (2 rows)
    const int cg  = tid & 31;        // 0..31 : GEMM col group (4 cols)
    const int r0  = rg * 2, c0 = cg * 4;
    const size_t rowg = (size_t)blockIdx.x * BR;

    for (int t = 0; t < TT; ++t) {
        __syncthreads();
        // ---------- step 1: state = 0.618*(LN(h)*g+b) + 0.382*(x_t @ Wi + bi) ----------
        {
            const float* xp = x + (rowg + (size_t)rLN) * (TT * NB) + (size_t)t * NB;
            float4 xa = *(const float4*)(xp);
            float4 xb = *(const float4*)(xp + 4);
            double xv[8] = {(double)xa.x, (double)xa.y, (double)xa.z, (double)xa.w,
                            (double)xb.x, (double)xb.y, (double)xb.z, (double)xb.w};

            double v[8];
            #pragma unroll
            for (int j = 0; j < 8; ++j) v[j] = sStateD[rLN][d0 + j];

            double sum = 0.0;
            #pragma unroll
            for (int j = 0; j < 8; ++j) sum += v[j];
            sum += __shfl_xor(sum, 1); sum += __shfl_xor(sum, 2);
            sum += __shfl_xor(sum, 4); sum += __shfl_xor(sum, 8);
            double mu = sum * (1.0 / 128.0);
            double sq = 0.0;
            #pragma unroll
            for (int j = 0; j < 8; ++j) { double dd = v[j] - mu; sq += dd * dd; }
            sq += __shfl_xor(sq, 1); sq += __shfl_xor(sq, 2);
            sq += __shfl_xor(sq, 4); sq += __shfl_xor(sq, 8);
            double rstd = 1.0 / sqrt(sq * (1.0 / 128.0) + 1e-5);

            #pragma unroll
            for (int j = 0; j < 8; ++j) {
                double inp = (double)sBi[d0 + j];
                #pragma unroll
                for (int k = 0; k < 8; ++k)
                    inp = fma(xv[k], (double)sWi[k][d0 + j], inp);
                double ln = (v[j] - mu) * rstd * (double)sGst[d0 + j] + (double)sBst[d0 + j];
                sStateD[rLN][d0 + j] = 0.618 * ln + 0.382 * inp;
            }
        }
        __syncthreads();

        // ---------- step 2: 3 residual layers (all fp64) ----------
        for (int layer = 0; layer < NL; ++layer) {
            {
                double v[8];
                #pragma unroll
                for (int j = 0; j < 8; ++j) v[j] = sStateD[rLN][d0 + j];
                double sum = 0.0;
                #pragma unroll
                for (int j = 0; j < 8; ++j) sum += v[j];
                sum += __shfl_xor(sum, 1); sum += __shfl_xor(sum, 2);
                sum += __shfl_xor(sum, 4); sum += __shfl_xor(sum, 8);
                double mu = sum * (1.0 / 128.0);
                double sq = 0.0;
                #pragma unroll
                for (int j = 0; j < 8; ++j) { double dd = v[j] - mu; sq += dd * dd; }
                sq += __shfl_xor(sq, 1); sq += __shfl_xor(sq, 2);
                sq += __shfl_xor(sq, 4); sq += __shfl_xor(sq, 8);
                double rstd = 1.0 / sqrt(sq * (1.0 / 128.0) + 1e-5);
                #pragma unroll
                for (int j = 0; j < 8; ++j)
                    sAD[rLN][d0 + j] = (v[j] - mu) * rstd * (double)sGs[layer][d0 + j]
                                       + (double)sBe[layer][d0 + j];
            }
            {
                const float* wsrc = Ws + (size_t)layer * D * D;
                #pragma unroll
                for (int it = 0; it < 8; ++it) {
                    int idx = it * (BDIM * 4) + tid * 4;
                    *(float4*)&sW[0][idx] = *(const float4*)&wsrc[idx];
                }
            }
            __syncthreads();

            // GEMM fp64: 2x4 tile per thread
            double acc[2][4];
            #pragma unroll
            for (int i = 0; i < 2; ++i)
                #pragma unroll
                for (int j = 0; j < 4; ++j) acc[i][j] = 0.0;

            for (int k0 = 0; k0 < D; k0 += 4) {
                double a0[4], a1[4];
                #pragma unroll
                for (int k = 0; k < 4; ++k) { a0[k] = sAD[r0][k0 + k]; a1[k] = sAD[r0 + 1][k0 + k]; }
                #pragma unroll
                for (int k = 0; k < 4; ++k) {
                    float4 w4 = *(const float4*)&sW[k0 + k][c0];
                    double b0 = (double)w4.x, b1 = (double)w4.y, b2 = (double)w4.z, b3 = (double)w4.w;
                    acc[0][0] = fma(a0[k], b0, acc[0][0]);
                    acc[0][1] = fma(a0[k], b1, acc[0][1]);
                    acc[0][2] = fma(a0[k], b2, acc[0][2]);
                    acc[0][3] = fma(a0[k], b3, acc[0][3]);
                    acc[1][0] = fma(a1[k], b0, acc[1][0]);
                    acc[1][1] = fma(a1[k], b1, acc[1][1]);
                    acc[1][2] = fma(a1[k], b2, acc[1][2]);
                    acc[1][3] = fma(a1[k], b3, acc[1][3]);
                }
            }
            #pragma unroll
            for (int i = 0; i < 2; ++i) {
                #pragma unroll
                for (int j = 0; j < 4; ++j) {
                    double y = acc[i][j] + (double)sBs[layer][c0 + j];
                    sStateD[r0 + i][c0 + j] += c19_act_d(y);
                }
            }
            __syncthreads();
        }

        // ---------- step 3: out = state @ Wo + bo (fp64, single fp32 rounding) ----------
        {
            double accj[8];
            #pragma unroll
            for (int j = 0; j < 8; ++j) accj[j] = 0.0;
            #pragma unroll
            for (int u = 0; u < 8; ++u) {
                int k = d0 + u;
                double s = sStateD[rLN][k];
                float4 w0 = *(const float4*)&sWo[k][0];
                float4 w1 = *(const float4*)&sWo[k][4];
                accj[0] = fma(s, (double)w0.x, accj[0]);
                accj[1] = fma(s, (double)w0.y, accj[1]);
                accj[2] = fma(s, (double)w0.z, accj[2]);
                accj[3] = fma(s, (double)w0.w, accj[3]);
                accj[4] = fma(s, (double)w1.x, accj[4]);
                accj[5] = fma(s, (double)w1.y, accj[5]);
                accj[6] = fma(s, (double)w1.z, accj[6]);
                accj[7] = fma(s, (double)w1.w, accj[7]);
            }
            #pragma unroll
            for (int j = 0; j < 8; ++j) {
                accj[j] += __shfl_xor(accj[j], 1);
                accj[j] += __shfl_xor(accj[j], 2);
                accj[j] += __shfl_xor(accj[j], 4);
                accj[j] += __shfl_xor(accj[j], 8);
            }
            if (sLN < NB)
                out[((rowg + (size_t)rLN) * TT + (size_t)t) * NB + sLN] =
                    (float)(accj[sLN] + (double)sBo[sLN]);
        }
    }
}

extern "C" void kernel_launch(void* const* d_in, const int* in_sizes, int n_in,
                              void* d_out, int out_size, void* d_ws, size_t ws_size,
                              hipStream_t stream) {
    const float* x       = (const float*)d_in[0];
    const float* Wi      = (const float*)d_in[1];
    const float* bi      = (const float*)d_in[2];
    const float* Wo      = (const float*)d_in[3];
    const float* bo      = (const float*)d_in[4];
    const float* g_state = (const float*)d_in[5];
    const float* b_state = (const float*)d_in[6];
    const float* Ws      = (const float*)d_in[7];
    const float* bs      = (const float*)d_in[8];
    const float* gs      = (const float*)d_in[9];
    const float* betas   = (const float*)d_in[10];
    float* out = (float*)d_out;

    const int B = in_sizes[0] / (TT * NB);   // 65536
    dim3 grid(B / BR), block(BDIM);
    hipLaunchKernelGGL(miniphi_kernel, grid, block, 0, stream,
                       x, Wi, bi, Wo, bo, g_state, b_state, Ws, bs, gs, betas, out);
}

// Round 6
// 8946.882 us; speedup vs baseline: 1.0171x; 1.0171x over previous
//
#include <hip/hip_runtime.h>
#include <math.h>

#define BDIM 512
#define BR   32
#define D    128
#define SPD  130      // state/A LDS row stride (doubles)
#define WTP  129      // transposed-W LDS row stride (floats)
#define SWOP 12       // sWo row stride (floats)
#define TT   32
#define NB   8
#define NL   3

__device__ __forceinline__ double c19_act_d(double x) {
    const double PI_D = 3.14159265358979323846;
    const double L6   = 6.0 * PI_D;
    double scaled = x * (1.0 / PI_D);
    double n = floor(scaled);
    double t = scaled - n;
    double h = t * (1.0 - t);
    double halfn = n * 0.5;
    double fr = halfn - floor(halfn);   // 0.0 (even n) or 0.5 (odd n)
    double sgn = (fr < 0.25) ? 1.0 : -1.0;
    double core = PI_D * (sgn * h + 4.0 * h * h);
    double r = core;
    r = (x <= -L6) ? (x + L6) : r;
    r = (x >=  L6) ? (x - L6) : r;
    return r;
}

__global__ __launch_bounds__(BDIM, 1) void miniphi_kernel(
    const float* __restrict__ x,  const float* __restrict__ Wi, const float* __restrict__ bi,
    const float* __restrict__ Wo, const float* __restrict__ bo,
    const float* __restrict__ g_state, const float* __restrict__ b_state,
    const float* __restrict__ Ws, const float* __restrict__ bs,
    const float* __restrict__ gs, const float* __restrict__ betas,
    float* __restrict__ out)
{
    __shared__ double sStateD[BR][SPD];   // recurrent state, fp64
    __shared__ double sAD[BR][SPD];       // LN output, fp64
    __shared__ float  sWT[D][WTP];        // current layer W, TRANSPOSED: sWT[n][k] = W[k][n]
    __shared__ float  sWi[NB][D];
    __shared__ float  sWo[D][SWOP];
    __shared__ float  sBi[D], sGst[D], sBst[D];
    __shared__ float  sBs[NL][D], sGs[NL][D], sBe[NL][D];
    __shared__ float  sBo[NB];

    const int tid = threadIdx.x;

    for (int i = tid; i < NB * D; i += BDIM) sWi[i / D][i % D] = Wi[i];
    for (int i = tid; i < D * NB; i += BDIM) sWo[i / NB][i % NB] = Wo[i];
    for (int i = tid; i < D; i += BDIM) { sBi[i] = bi[i]; sGst[i] = g_state[i]; sBst[i] = b_state[i]; }
    for (int i = tid; i < NL * D; i += BDIM) { sBs[i / D][i % D] = bs[i]; sGs[i / D][i % D] = gs[i]; sBe[i / D][i % D] = betas[i]; }
    if (tid < NB) sBo[tid] = bo[tid];
    for (int i = tid; i < BR * D; i += BDIM) sStateD[i / D][i % D] = 0.0;
    __syncthreads();

    const int rLN = tid >> 4;        // 0..31 : row for LN phases (16 lanes/row)
    const int sLN = tid & 15;        // 0..15 : lane owns cols {sLN + 16*j}
    const int wrg = tid >> 6;        // 0..7  : GEMM row group (4 rows), whole wave
    const int cg  = tid & 63;        // 0..63 : GEMM cols {cg, cg+64}
    const int r0  = wrg * 4;
    const size_t rowg = (size_t)blockIdx.x * BR;

    for (int t = 0; t < TT; ++t) {
        __syncthreads();
        // ---------- step 1: state = 0.618*(LN(h)*g+b) + 0.382*(x_t @ Wi + bi) ----------
        {
            const float* xp = x + (rowg + (size_t)rLN) * (TT * NB) + (size_t)t * NB;
            float4 xa = *(const float4*)(xp);
            float4 xb = *(const float4*)(xp + 4);
            double xv[8] = {(double)xa.x, (double)xa.y, (double)xa.z, (double)xa.w,
                            (double)xb.x, (double)xb.y, (double)xb.z, (double)xb.w};

            double v[8];
            #pragma unroll
            for (int j = 0; j < 8; ++j) v[j] = sStateD[rLN][sLN + 16 * j];

            double sum = 0.0;
            #pragma unroll
            for (int j = 0; j < 8; ++j) sum += v[j];
            sum += __shfl_xor(sum, 1); sum += __shfl_xor(sum, 2);
            sum += __shfl_xor(sum, 4); sum += __shfl_xor(sum, 8);
            double mu = sum * (1.0 / 128.0);
            double sq = 0.0;
            #pragma unroll
            for (int j = 0; j < 8; ++j) { double dd = v[j] - mu; sq += dd * dd; }
            sq += __shfl_xor(sq, 1); sq += __shfl_xor(sq, 2);
            sq += __shfl_xor(sq, 4); sq += __shfl_xor(sq, 8);
            double rstd = 1.0 / sqrt(sq * (1.0 / 128.0) + 1e-5);

            #pragma unroll
            for (int j = 0; j < 8; ++j) {
                int c = sLN + 16 * j;
                double inp = (double)sBi[c];
                #pragma unroll
                for (int k = 0; k < 8; ++k)
                    inp = fma(xv[k], (double)sWi[k][c], inp);
                double ln = (v[j] - mu) * rstd * (double)sGst[c] + (double)sBst[c];
                sStateD[rLN][c] = 0.618 * ln + 0.382 * inp;
            }
        }
        __syncthreads();

        // ---------- step 2: 3 residual layers (fp64 VALU GEMM) ----------
        for (int layer = 0; layer < NL; ++layer) {
            // LN(state) -> sAD
            {
                double v[8];
                #pragma unroll
                for (int j = 0; j < 8; ++j) v[j] = sStateD[rLN][sLN + 16 * j];
                double sum = 0.0;
                #pragma unroll
                for (int j = 0; j < 8; ++j) sum += v[j];
                sum += __shfl_xor(sum, 1); sum += __shfl_xor(sum, 2);
                sum += __shfl_xor(sum, 4); sum += __shfl_xor(sum, 8);
                double mu = sum * (1.0 / 128.0);
                double sq = 0.0;
                #pragma unroll
                for (int j = 0; j < 8; ++j) { double dd = v[j] - mu; sq += dd * dd; }
                sq += __shfl_xor(sq, 1); sq += __shfl_xor(sq, 2);
                sq += __shfl_xor(sq, 4); sq += __shfl_xor(sq, 8);
                double rstd = 1.0 / sqrt(sq * (1.0 / 128.0) + 1e-5);
                #pragma unroll
                for (int j = 0; j < 8; ++j) {
                    int c = sLN + 16 * j;
                    sAD[rLN][c] = (v[j] - mu) * rstd * (double)sGs[layer][c]
                                  + (double)sBe[layer][c];
                }
            }
            // stage W transposed: sWT[n][k] = W[k][n]
            {
                const float* wsrc = Ws + (size_t)layer * D * D;
                #pragma unroll
                for (int it = 0; it < 8; ++it) {
                    int i = it * (BDIM * 4) + tid * 4;
                    float4 w4 = *(const float4*)&wsrc[i];
                    int k = i >> 7, n = i & 127;
                    sWT[n + 0][k] = w4.x;
                    sWT[n + 1][k] = w4.y;
                    sWT[n + 2][k] = w4.z;
                    sWT[n + 3][k] = w4.w;
                }
            }
            __syncthreads();

            // GEMM: 4 rows x 2 cols per thread; A broadcast per wave, B via sWT
            double acc[4][2];
            #pragma unroll
            for (int r = 0; r < 4; ++r) { acc[r][0] = 0.0; acc[r][1] = 0.0; }

            for (int k0 = 0; k0 < D; k0 += 4) {
                double2 a01[4], a23[4];
                #pragma unroll
                for (int r = 0; r < 4; ++r) {
                    a01[r] = *(const double2*)&sAD[r0 + r][k0];
                    a23[r] = *(const double2*)&sAD[r0 + r][k0 + 2];
                }
                float4 b0 = *(const float4*)&sWT[cg][k0];
                float4 b1 = *(const float4*)&sWT[cg + 64][k0];
                double b00 = (double)b0.x, b01 = (double)b0.y, b02 = (double)b0.z, b03 = (double)b0.w;
                double b10 = (double)b1.x, b11 = (double)b1.y, b12 = (double)b1.z, b13 = (double)b1.w;
                #pragma unroll
                for (int r = 0; r < 4; ++r) {
                    double t0 = acc[r][0], t1 = acc[r][1];
                    t0 = fma(a01[r].x, b00, t0);
                    t0 = fma(a01[r].y, b01, t0);
                    t0 = fma(a23[r].x, b02, t0);
                    t0 = fma(a23[r].y, b03, t0);
                    t1 = fma(a01[r].x, b10, t1);
                    t1 = fma(a01[r].y, b11, t1);
                    t1 = fma(a23[r].x, b12, t1);
                    t1 = fma(a23[r].y, b13, t1);
                    acc[r][0] = t0; acc[r][1] = t1;
                }
            }
            // residual: state += c19(Y + bs)
            {
                double bs0 = (double)sBs[layer][cg];
                double bs1 = (double)sBs[layer][cg + 64];
                #pragma unroll
                for (int r = 0; r < 4; ++r) {
                    sStateD[r0 + r][cg]      += c19_act_d(acc[r][0] + bs0);
                    sStateD[r0 + r][cg + 64] += c19_act_d(acc[r][1] + bs1);
                }
            }
            __syncthreads();
        }

        // ---------- step 3: out = state @ Wo + bo (fp64, single fp32 rounding) ----------
        {
            double accj[8];
            #pragma unroll
            for (int j = 0; j < 8; ++j) accj[j] = 0.0;
            #pragma unroll
            for (int u = 0; u < 8; ++u) {
                int k = sLN + 16 * u;
                double s = sStateD[rLN][k];
                float4 w0 = *(const float4*)&sWo[k][0];
                float4 w1 = *(const float4*)&sWo[k][4];
                accj[0] = fma(s, (double)w0.x, accj[0]);
                accj[1] = fma(s, (double)w0.y, accj[1]);
                accj[2] = fma(s, (double)w0.z, accj[2]);
                accj[3] = fma(s, (double)w0.w, accj[3]);
                accj[4] = fma(s, (double)w1.x, accj[4]);
                accj[5] = fma(s, (double)w1.y, accj[5]);
                accj[6] = fma(s, (double)w1.z, accj[6]);
                accj[7] = fma(s, (double)w1.w, accj[7]);
            }
            #pragma unroll
            for (int j = 0; j < 8; ++j) {
                accj[j] += __shfl_xor(accj[j], 1);
                accj[j] += __shfl_xor(accj[j], 2);
                accj[j] += __shfl_xor(accj[j], 4);
                accj[j] += __shfl_xor(accj[j], 8);
            }
            if (sLN < NB)
                out[((rowg + (size_t)rLN) * TT + (size_t)t) * NB + sLN] =
                    (float)(accj[sLN] + (double)sBo[sLN]);
        }
    }
}

extern "C" void kernel_launch(void* const* d_in, const int* in_sizes, int n_in,
                              void* d_out, int out_size, void* d_ws, size_t ws_size,
                              hipStream_t stream) {
    const float* x       = (const float*)d_in[0];
    const float* Wi      = (const float*)d_in[1];
    const float* bi      = (const float*)d_in[2];
    const float* Wo      = (const float*)d_in[3];
    const float* bo      = (const float*)d_in[4];
    const float* g_state = (const float*)d_in[5];
    const float* b_state = (const float*)d_in[6];
    const float* Ws      = (const float*)d_in[7];
    const float* bs      = (const float*)d_in[8];
    const float* gs      = (const float*)d_in[9];
    const float* betas   = (const float*)d_in[10];
    float* out = (float*)d_out;

    const int B = in_sizes[0] / (TT * NB);   // 65536
    dim3 grid(B / BR), block(BDIM);
    hipLaunchKernelGGL(miniphi_kernel, grid, block, 0, stream,
                       x, Wi, bi, Wo, bo, g_state, b_state, Ws, bs, gs, betas, out);
}